// Round 1
// baseline (240.642 us; speedup 1.0000x reference)
//
#include <hip/hip_runtime.h>

#define HWsz 16384
#define CH   256
#define NB   8
#define EPSV 1e-5f

// ---------------------------------------------------------------------------
// K1: per-(b,c) sum and sum-of-squares over H*W (16384 elems). 2048 blocks.
// ---------------------------------------------------------------------------
__global__ __launch_bounds__(256) void stats_kernel(const float* __restrict__ x,
                                                    float* __restrict__ sums,
                                                    float* __restrict__ sumsq) {
    const int bc  = blockIdx.x;
    const int tid = threadIdx.x;
    const float4* p = reinterpret_cast<const float4*>(x + (size_t)bc * HWsz);
    float s = 0.f, q = 0.f;
#pragma unroll 4
    for (int i = tid; i < HWsz / 4; i += 256) {
        float4 v = p[i];
        s += v.x + v.y + v.z + v.w;
        q += v.x * v.x + v.y * v.y + v.z * v.z + v.w * v.w;
    }
    __shared__ float rs[256], rq[256];
    rs[tid] = s; rq[tid] = q;
    __syncthreads();
    for (int off = 128; off > 0; off >>= 1) {
        if (tid < off) { rs[tid] += rs[tid + off]; rq[tid] += rq[tid + off]; }
        __syncthreads();
    }
    if (tid == 0) { sums[bc] = rs[0]; sumsq[bc] = rq[0]; }
}

// ---------------------------------------------------------------------------
// K2: per-b — finalize IN/LN stats, fold norms+gamma into A' (stored [b][c][o],
// c-major so GEMM staging is coalesced) and bias D'. 8 blocks x 256 threads.
// ---------------------------------------------------------------------------
__global__ __launch_bounds__(256) void prep_kernel(const float* __restrict__ sums,
                                                   const float* __restrict__ sumsq,
                                                   const float* __restrict__ params,
                                                   const float* __restrict__ W,
                                                   float* __restrict__ Ap,
                                                   float* __restrict__ Dp) {
    const int b   = blockIdx.x;
    const int tid = threadIdx.x;
    __shared__ float mu[CH], ri[CH], rs[CH], rq[CH];
    float s = sums[b * CH + tid];
    float q = sumsq[b * CH + tid];
    float m = s * (1.0f / HWsz);
    float v = q * (1.0f / HWsz) - m * m;
    mu[tid] = m;
    ri[tid] = rsqrtf(v + EPSV);
    rs[tid] = s; rq[tid] = q;
    __syncthreads();
    for (int off = 128; off > 0; off >>= 1) {
        if (tid < off) { rs[tid] += rs[tid + off]; rq[tid] += rq[tid + off]; }
        __syncthreads();
    }
    const float invN = 1.0f / ((float)CH * (float)HWsz);
    const float mln  = rs[0] * invN;
    const float vln  = rq[0] * invN - mln * mln;
    const float rln  = rsqrtf(vln + EPSV);

    // each thread owns output channel o = tid
    const int o = tid;
    const float gamma = params[b * 2 * CH + o];
    const float beta  = params[b * 2 * CH + CH + o];
    const float4* w1p = reinterpret_cast<const float4*>(W + (size_t)o * 2 * CH);
    const float4* w2p = reinterpret_cast<const float4*>(W + (size_t)o * 2 * CH + CH);
    float t1 = 0.f, t2 = 0.f;
    for (int c4 = 0; c4 < CH / 4; ++c4) {
        float4 w1 = w1p[c4];
        float4 w2 = w2p[c4];
        float w1a[4] = {w1.x, w1.y, w1.z, w1.w};
        float w2a[4] = {w2.x, w2.y, w2.z, w2.w};
        const int c = c4 * 4;
#pragma unroll
        for (int j = 0; j < 4; ++j) {
            float ric = ri[c + j];
            float a   = w1a[j] * ric + w2a[j] * rln;
            Ap[((size_t)(b * CH + c + j)) * CH + o] = gamma * a;
            t1 += w1a[j] * ric * mu[c + j];
            t2 += w2a[j];
        }
    }
    const float d = -(t1 + rln * mln * t2);
    Dp[b * CH + o] = gamma * d + beta;
}

// ---------------------------------------------------------------------------
// K3: batched GEMM  out[b][o][n] = sum_c A'[b][c][o] * x[b][c][n] + D'[b][o]
// Block tile 128(m) x 128(n), K-step 16, 256 threads, 8x8 register tile
// (split 4+4 so LDS reads are broadcast / 2-way conflict-free).
// ---------------------------------------------------------------------------
__global__ __launch_bounds__(256) void gemm_kernel(const float* __restrict__ x,
                                                   const float* __restrict__ Ap,
                                                   const float* __restrict__ Dp,
                                                   float* __restrict__ out) {
    const int n0  = blockIdx.x * 128;
    const int m0  = blockIdx.y * 128;
    const int b   = blockIdx.z;
    const int tid = threadIdx.x;
    const int tm  = tid >> 4;   // 0..15
    const int tn  = tid & 15;   // 0..15

    __shared__ float As[16][128];
    __shared__ float Xs[16][128];

    float acc[8][8];
#pragma unroll
    for (int i = 0; i < 8; ++i)
#pragma unroll
        for (int j = 0; j < 8; ++j) acc[i][j] = 0.f;

    const size_t xbase = (size_t)b * CH * HWsz;
    const size_t abase = (size_t)b * CH * CH;

    for (int kb = 0; kb < CH / 16; ++kb) {
        __syncthreads();
#pragma unroll
        for (int i = 0; i < 2; ++i) {
            const int ff = tid + i * 256;
            const int kk = ff >> 5;
            const int q4 = (ff & 31) * 4;
            *reinterpret_cast<float4*>(&As[kk][q4]) =
                *reinterpret_cast<const float4*>(Ap + abase + (size_t)(kb * 16 + kk) * CH + m0 + q4);
            *reinterpret_cast<float4*>(&Xs[kk][q4]) =
                *reinterpret_cast<const float4*>(x + xbase + (size_t)(kb * 16 + kk) * HWsz + n0 + q4);
        }
        __syncthreads();
#pragma unroll
        for (int k = 0; k < 16; ++k) {
            float4 a0 = *reinterpret_cast<const float4*>(&As[k][tm * 4]);
            float4 a1 = *reinterpret_cast<const float4*>(&As[k][64 + tm * 4]);
            float4 x0 = *reinterpret_cast<const float4*>(&Xs[k][tn * 4]);
            float4 x1 = *reinterpret_cast<const float4*>(&Xs[k][64 + tn * 4]);
            float am[8] = {a0.x, a0.y, a0.z, a0.w, a1.x, a1.y, a1.z, a1.w};
            float xn[8] = {x0.x, x0.y, x0.z, x0.w, x1.x, x1.y, x1.z, x1.w};
#pragma unroll
            for (int i = 0; i < 8; ++i)
#pragma unroll
                for (int j = 0; j < 8; ++j)
                    acc[i][j] = fmaf(am[i], xn[j], acc[i][j]);
        }
    }

#pragma unroll
    for (int i = 0; i < 8; ++i) {
        const int m = m0 + ((i < 4) ? (tm * 4 + i) : (64 + tm * 4 + (i - 4)));
        const float dv = Dp[b * CH + m];
        float4 v0 = make_float4(acc[i][0] + dv, acc[i][1] + dv, acc[i][2] + dv, acc[i][3] + dv);
        float4 v1 = make_float4(acc[i][4] + dv, acc[i][5] + dv, acc[i][6] + dv, acc[i][7] + dv);
        float* orow = out + (size_t)(b * CH + m) * HWsz + n0;
        *reinterpret_cast<float4*>(orow + tn * 4)      = v0;
        *reinterpret_cast<float4*>(orow + 64 + tn * 4) = v1;
    }
}

// ---------------------------------------------------------------------------
extern "C" void kernel_launch(void* const* d_in, const int* in_sizes, int n_in,
                              void* d_out, int out_size, void* d_ws, size_t ws_size,
                              hipStream_t stream) {
    const float* x      = (const float*)d_in[0];
    const float* params = (const float*)d_in[1];
    const float* W      = (const float*)d_in[2];
    float* out = (float*)d_out;
    float* ws  = (float*)d_ws;

    float* sums  = ws;          // 2048 floats
    float* sumsq = ws + 2048;   // 2048 floats
    float* Dp    = ws + 4096;   // 2048 floats
    float* Ap    = ws + 8192;   // 524288 floats (A' as [b][c][o])

    hipLaunchKernelGGL(stats_kernel, dim3(NB * CH), dim3(256), 0, stream, x, sums, sumsq);
    hipLaunchKernelGGL(prep_kernel,  dim3(NB),      dim3(256), 0, stream, sums, sumsq, params, W, Ap, Dp);
    hipLaunchKernelGGL(gemm_kernel,  dim3(HWsz / 128, CH / 128, NB), dim3(256), 0, stream, x, Ap, Dp, out);
}

// Round 3
// 116.223 us; speedup vs baseline: 2.0705x; 2.0705x over previous
//
#include <hip/hip_runtime.h>
#include <stdint.h>

#define HW_  16384
#define CH   256
#define NB   8
#define EPSV 1e-5f

typedef float f32x4 __attribute__((ext_vector_type(4)));
typedef short s16x8 __attribute__((ext_vector_type(8)));

__device__ __forceinline__ unsigned short f2bf(float f) {
    union { float f; uint32_t u; } v; v.f = f;
    uint32_t r = (v.u + 0x7FFFu + ((v.u >> 16) & 1u)) >> 16;  // RNE
    return (unsigned short)r;
}

// ---------------------------------------------------------------------------
// K1: per-(b,c) sum and sum-of-squares over H*W. 2048 blocks x 256 thr.
// ---------------------------------------------------------------------------
__global__ __launch_bounds__(256) void stats_kernel(const float* __restrict__ x,
                                                    float* __restrict__ sums,
                                                    float* __restrict__ sumsq) {
    const int bc  = blockIdx.x;
    const int tid = threadIdx.x;
    const float4* p = reinterpret_cast<const float4*>(x + (size_t)bc * HW_);
    float s = 0.f, q = 0.f;
#pragma unroll 4
    for (int i = tid; i < HW_ / 4; i += 256) {
        float4 v = p[i];
        s += v.x + v.y + v.z + v.w;
        q += v.x * v.x + v.y * v.y + v.z * v.z + v.w * v.w;
    }
    __shared__ float rs[256], rq[256];
    rs[tid] = s; rq[tid] = q;
    __syncthreads();
    for (int off = 128; off > 0; off >>= 1) {
        if (tid < off) { rs[tid] += rs[tid + off]; rq[tid] += rq[tid + off]; }
        __syncthreads();
    }
    if (tid == 0) { sums[bc] = rs[0]; sumsq[bc] = rq[0]; }
}

// ---------------------------------------------------------------------------
// K2: finalize stats, fold into A' (bf16, [b][o][c], c contiguous) + D' (f32).
// ---------------------------------------------------------------------------
__global__ __launch_bounds__(256) void prep_kernel(const float* __restrict__ sums,
                                                   const float* __restrict__ sumsq,
                                                   const float* __restrict__ params,
                                                   const float* __restrict__ W,
                                                   unsigned short* __restrict__ Ap,
                                                   float* __restrict__ Dp) {
    const int b   = blockIdx.x;
    const int tid = threadIdx.x;
    __shared__ float mu[CH], ri[CH], rs[CH], rq[CH];
    float s = sums[b * CH + tid];
    float q = sumsq[b * CH + tid];
    float m = s * (1.0f / HW_);
    float v = q * (1.0f / HW_) - m * m;
    mu[tid] = m;
    ri[tid] = rsqrtf(v + EPSV);
    rs[tid] = s; rq[tid] = q;
    __syncthreads();
    for (int off = 128; off > 0; off >>= 1) {
        if (tid < off) { rs[tid] += rs[tid + off]; rq[tid] += rq[tid + off]; }
        __syncthreads();
    }
    const float invN = 1.0f / ((float)CH * (float)HW_);
    const float mln  = rs[0] * invN;
    const float vln  = rq[0] * invN - mln * mln;
    const float rln  = rsqrtf(vln + EPSV);

    const int o = tid;
    const float gamma = params[b * 2 * CH + o];
    const float beta  = params[b * 2 * CH + CH + o];
    const float4* w1p = reinterpret_cast<const float4*>(W + (size_t)o * 2 * CH);
    const float4* w2p = reinterpret_cast<const float4*>(W + (size_t)o * 2 * CH + CH);
    unsigned short* aprow = Ap + ((size_t)(b * CH + o)) * CH;
    float t1 = 0.f, t2 = 0.f;
    for (int c4 = 0; c4 < CH / 4; ++c4) {
        float4 w1 = w1p[c4];
        float4 w2 = w2p[c4];
        float w1a[4] = {w1.x, w1.y, w1.z, w1.w};
        float w2a[4] = {w2.x, w2.y, w2.z, w2.w};
        const int c = c4 * 4;
        ushort4 pk;
        unsigned short* pka = (unsigned short*)&pk;
#pragma unroll
        for (int j = 0; j < 4; ++j) {
            float ric = ri[c + j];
            float a   = gamma * (w1a[j] * ric + w2a[j] * rln);
            pka[j] = f2bf(a);
            t1 += w1a[j] * ric * mu[c + j];
            t2 += w2a[j];
        }
        *reinterpret_cast<ushort4*>(aprow + c) = pk;
    }
    const float d = -(t1 + rln * mln * t2);
    Dp[b * CH + o] = gamma * d + beta;
}

// ---------------------------------------------------------------------------
// K3: batched MFMA GEMM.  out[b][m][n] = sum_c A'[b][m][c] * x[b][c][n] + D'
// BM=256 (all M), BN=128, BK=32. 512 threads = 8 waves, wave grid 4(m)x2(n),
// wave tile 64x64 = 4x4 fragments of 16x16x32 bf16 MFMA.
// LDS subtiled [g][row][8] (g = k-octet) so fragment reads are ds_read_b128.
// x transposed c-major -> k-contiguous during staging via pair-packed b32.
// ---------------------------------------------------------------------------
__global__ __launch_bounds__(512) void gemm_kernel(const float* __restrict__ x,
                                                   const unsigned short* __restrict__ Ap,
                                                   const float* __restrict__ Dp,
                                                   float* __restrict__ out) {
    __shared__ unsigned short As[4 * 256 * 8];  // [g][m][8]  A'[m][k0+8g+e]
    __shared__ unsigned short Xs[4 * 128 * 8];  // [g][n][8]  x[k0+8g+e][n0+n]

    const int b   = blockIdx.y;
    const int n0  = blockIdx.x * 128;
    const int t   = threadIdx.x;
    const int w   = t >> 6;
    const int l   = t & 63;
    const int wm  = w >> 1;        // 0..3
    const int wn  = w & 1;         // 0..1
    const int lhi = l >> 4;        // 0..3 (k-group)
    const int llo = l & 15;        // row/col within fragment

    // acc init = bias D' (C-operand of MFMA): D row = wm*64+fm*16+lhi*4+r
    f32x4 acc[4][4];
    const float* dpb = Dp + b * CH;
#pragma unroll
    for (int fm = 0; fm < 4; ++fm) {
        const int mb = wm * 64 + fm * 16 + lhi * 4;
        f32x4 d;
        d.x = dpb[mb + 0]; d.y = dpb[mb + 1]; d.z = dpb[mb + 2]; d.w = dpb[mb + 3];
#pragma unroll
        for (int fn = 0; fn < 4; ++fn) acc[fm][fn] = d;
    }

    const size_t xbase = (size_t)b * CH * HW_ + n0;
    const unsigned short* apb = Ap + (size_t)b * CH * CH;
    uint32_t* Xs32 = reinterpret_cast<uint32_t*>(Xs);

    // staging index precompute
    const int am  = t & 255;            // A' row m
    const int ag0 = t >> 8;             // g for i=0 (i=1 -> +2)
    const int kp  = t >> 5;             // x k-pair 0..15 (rows 2kp, 2kp+1)
    const int nq  = t & 31;             // x n-quad 0..31 (coalesced: half-wave = 512B row segment)
    const int xg  = kp >> 2;            // Xs g
    const int xh  = kp & 3;             // u32 slot within octet

    for (int kb = 0; kb < 8; ++kb) {
        const int k0 = kb * 32;
        // global loads into regs (overlap with previous tile's MFMA drain)
        s16x8 areg0 = *reinterpret_cast<const s16x8*>(apb + (size_t)am * CH + k0 + (ag0 + 0) * 8);
        s16x8 areg1 = *reinterpret_cast<const s16x8*>(apb + (size_t)am * CH + k0 + (ag0 + 2) * 8);
        f32x4 xa = *reinterpret_cast<const f32x4*>(x + xbase + (size_t)(k0 + 2 * kp + 0) * HW_ + nq * 4);
        f32x4 xb = *reinterpret_cast<const f32x4*>(x + xbase + (size_t)(k0 + 2 * kp + 1) * HW_ + nq * 4);

        __syncthreads();  // previous tile fully consumed

        *reinterpret_cast<s16x8*>(&As[(ag0 + 0) * 2048 + am * 8]) = areg0;
        *reinterpret_cast<s16x8*>(&As[(ag0 + 2) * 2048 + am * 8]) = areg1;
#pragma unroll
        for (int j = 0; j < 4; ++j) {
            uint32_t pk = (uint32_t)f2bf(xa[j]) | ((uint32_t)f2bf(xb[j]) << 16);
            Xs32[xg * 512 + (nq * 4 + j) * 4 + xh] = pk;   // [g]=512 u32 blocks (bug fix)
        }

        __syncthreads();  // tile ready

        s16x8 af[4], bfr[4];
#pragma unroll
        for (int fm = 0; fm < 4; ++fm)
            af[fm] = *reinterpret_cast<const s16x8*>(&As[lhi * 2048 + (wm * 64 + fm * 16 + llo) * 8]);
#pragma unroll
        for (int fn = 0; fn < 4; ++fn)
            bfr[fn] = *reinterpret_cast<const s16x8*>(&Xs[lhi * 1024 + (wn * 64 + fn * 16 + llo) * 8]);
#pragma unroll
        for (int fm = 0; fm < 4; ++fm)
#pragma unroll
            for (int fn = 0; fn < 4; ++fn)
                acc[fm][fn] = __builtin_amdgcn_mfma_f32_16x16x32_bf16(af[fm], bfr[fn], acc[fm][fn], 0, 0, 0);
    }

    // epilogue: bias already folded into acc
#pragma unroll
    for (int fm = 0; fm < 4; ++fm) {
        const int m = wm * 64 + fm * 16 + lhi * 4;
        float* obase = out + (size_t)(b * CH + m) * HW_ + n0 + wn * 64 + llo;
#pragma unroll
        for (int fn = 0; fn < 4; ++fn) {
#pragma unroll
            for (int r = 0; r < 4; ++r)
                obase[(size_t)r * HW_ + fn * 16] = acc[fm][fn][r];
        }
    }
}

// ---------------------------------------------------------------------------
extern "C" void kernel_launch(void* const* d_in, const int* in_sizes, int n_in,
                              void* d_out, int out_size, void* d_ws, size_t ws_size,
                              hipStream_t stream) {
    const float* x      = (const float*)d_in[0];
    const float* params = (const float*)d_in[1];
    const float* W      = (const float*)d_in[2];
    float* out = (float*)d_out;
    float* ws  = (float*)d_ws;

    float* sums  = ws;                 // 2048 f32
    float* sumsq = ws + 2048;          // 2048 f32
    float* Dp    = ws + 4096;          // 2048 f32
    unsigned short* Ap = (unsigned short*)(ws + 6144);  // 8*256*256 bf16 = 1 MB

    hipLaunchKernelGGL(stats_kernel, dim3(NB * CH), dim3(256), 0, stream, x, sums, sumsq);
    hipLaunchKernelGGL(prep_kernel,  dim3(NB),      dim3(256), 0, stream, sums, sumsq, params, W, Ap, Dp);
    hipLaunchKernelGGL(gemm_kernel,  dim3(HW_ / 128, NB), dim3(512), 0, stream, x, Ap, Dp, out);
}